// Round 1
// baseline (12.180 us; speedup 1.0000x reference)
//
#include <hip/hip_runtime.h>
#include <hip/hip_bf16.h>

#define NUM_CLASSES 21
#define M_PLUS 0.9f
#define M_MINUS 0.1f
#define LAMBDA 0.5f

// B=8, P=512*512=262144 pixels/image, total 2,097,152 labels.
// presence kernel: 2048 blocks x 256 threads, 4 labels/thread (int4).
// Each block covers 1024 consecutive labels -> exactly one batch
// (262144 % 1024 == 0). Block writes its 21-bit class-presence mask to
// ws[blockIdx.x]; blocks [b*256, (b+1)*256) belong to batch b.
__global__ void caps_presence_kernel(const int* __restrict__ labels,
                                     unsigned* __restrict__ block_masks) {
    int gid = blockIdx.x * blockDim.x + threadIdx.x;
    const int4* L = reinterpret_cast<const int4*>(labels);
    int4 v = L[gid];
    unsigned m = 0;
    if ((unsigned)v.x < (unsigned)NUM_CLASSES) m |= 1u << v.x;
    if ((unsigned)v.y < (unsigned)NUM_CLASSES) m |= 1u << v.y;
    if ((unsigned)v.z < (unsigned)NUM_CLASSES) m |= 1u << v.z;
    if ((unsigned)v.w < (unsigned)NUM_CLASSES) m |= 1u << v.w;

    // wave-64 OR reduce
    #pragma unroll
    for (int s = 1; s < 64; s <<= 1) m |= __shfl_xor(m, s, 64);

    __shared__ unsigned wm[4];
    int lane = threadIdx.x & 63;
    int w = threadIdx.x >> 6;
    if (lane == 0) wm[w] = m;
    __syncthreads();
    if (threadIdx.x == 0)
        block_masks[blockIdx.x] = wm[0] | wm[1] | wm[2] | wm[3];
}

// finalize: 1 block x 256 threads.
// Phase 1: OR the 2048 block masks into 8 per-batch presence words.
// Phase 2: 168 threads compute per-(b,c) margin; block-reduce sum; out = sum/8.
__global__ void caps_finalize_kernel(const float* __restrict__ caps,
                                     const unsigned* __restrict__ block_masks,
                                     float* __restrict__ out) {
    __shared__ unsigned pres[8];
    __shared__ float ssum[256];
    int t = threadIdx.x;

    // b = t>>5 in [0,8); j = t&31 in [0,32); each thread ORs 8 masks.
    int b = t >> 5, j = t & 31;
    unsigned m = 0;
    #pragma unroll
    for (int k = 0; k < 8; ++k) m |= block_masks[b * 256 + j * 8 + k];
    // reduce across the 32-lane group (xor masks < 32 stay within group)
    #pragma unroll
    for (int s = 16; s; s >>= 1) m |= __shfl_xor(m, s, 64);
    if (j == 0) pres[b] = m;
    __syncthreads();

    float v = 0.0f;
    if (t < 8 * NUM_CLASSES) {
        int bb = t / NUM_CLASSES, c = t % NUM_CLASSES;
        float s2 = 0.0f;
        #pragma unroll
        for (int d = 0; d < 16; ++d) {
            float x = caps[(bb * NUM_CLASSES + c) * 16 + d];
            s2 += x * x;
        }
        float len = sqrtf(s2);
        float present = ((pres[bb] >> c) & 1u) ? 1.0f : 0.0f;
        float left = fmaxf(M_PLUS - len, 0.0f);  left *= left;
        float right = fmaxf(len - M_MINUS, 0.0f); right *= right;
        v = present * left + LAMBDA * (1.0f - present) * right;
    }
    ssum[t] = v;
    __syncthreads();
    #pragma unroll
    for (int s = 128; s; s >>= 1) {
        if (t < s) ssum[t] += ssum[t + s];
        __syncthreads();
    }
    if (t == 0) out[0] = ssum[0] * 0.125f;  // mean over B=8
}

extern "C" void kernel_launch(void* const* d_in, const int* in_sizes, int n_in,
                              void* d_out, int out_size, void* d_ws, size_t ws_size,
                              hipStream_t stream) {
    const float* caps   = (const float*)d_in[0];  // [8,21,16] f32
    const int*   labels = (const int*)d_in[1];    // [8,512,512] i32
    float* out = (float*)d_out;
    unsigned* block_masks = (unsigned*)d_ws;      // 2048 words = 8 KiB

    caps_presence_kernel<<<2048, 256, 0, stream>>>(labels, block_masks);
    caps_finalize_kernel<<<1, 256, 0, stream>>>(caps, block_masks, out);
}

// Round 2
// 11.228 us; speedup vs baseline: 1.0848x; 1.0848x over previous
//
#include <hip/hip_runtime.h>
#include <hip/hip_bf16.h>

#define NUM_CLASSES 21
#define LAMBDA 0.5f

// B=8, 512*512 = 262144 labels/image, 2,097,152 total = 524288 int4.
// Kernel 1, blocks 0..255: each block scans 2048 consecutive int4 (8192 labels;
//   exactly 32 blocks per batch). Each thread: 8 independent int4 loads ->
//   21-bit class mask -> wave-64 shfl-OR -> each wave writes its own slot
//   bm[blk*4 + wave]. No __syncthreads, no LDS.
// Kernel 1, block 256: precompute the 168 (b,c) left/right margin terms from
//   class_caps in parallel with the label scan.
__global__ __launch_bounds__(256) void caps_fused1(
        const int* __restrict__ labels, const float* __restrict__ caps,
        unsigned* __restrict__ bm, float* __restrict__ lr) {
    int t = threadIdx.x;
    if (blockIdx.x < 256) {
        const int4* L = reinterpret_cast<const int4*>(labels)
                        + (size_t)blockIdx.x * 2048;
        unsigned m = 0;
        #pragma unroll
        for (int k = 0; k < 8; ++k) {
            int4 v = L[t + k * 256];
            if ((unsigned)v.x < (unsigned)NUM_CLASSES) m |= 1u << v.x;
            if ((unsigned)v.y < (unsigned)NUM_CLASSES) m |= 1u << v.y;
            if ((unsigned)v.z < (unsigned)NUM_CLASSES) m |= 1u << v.z;
            if ((unsigned)v.w < (unsigned)NUM_CLASSES) m |= 1u << v.w;
        }
        #pragma unroll
        for (int s = 1; s < 64; s <<= 1) m |= __shfl_xor(m, s, 64);
        if ((t & 63) == 0) bm[blockIdx.x * 4 + (t >> 6)] = m;
    } else {
        if (t < 8 * NUM_CLASSES) {          // t enumerates (b*21 + c)
            const float* p = caps + t * 16;
            float s2 = 0.0f;
            #pragma unroll
            for (int d = 0; d < 16; ++d) { float x = p[d]; s2 += x * x; }
            float len = sqrtf(s2);
            float l = fmaxf(0.9f - len, 0.0f);  l *= l;
            float r = fmaxf(len - 0.1f, 0.0f);  r *= r;
            lr[t] = l;
            lr[168 + t] = r;
        }
    }
}

// Kernel 2: 1 block x 256 threads, 2 barriers.
// Phase 1: 1024 mask words, 128 per batch. Thread t: b=t>>5, j=t&31 ORs 4
//   words; shfl-xor reduce across the aligned 32-lane group -> pres[8].
// Phase 2: 168 threads select precomputed left / 0.5*right; wave shfl sum +
//   one LDS combine -> out = sum/8.
__global__ __launch_bounds__(256) void caps_finalize(
        const unsigned* __restrict__ bm, const float* __restrict__ lr,
        float* __restrict__ out) {
    __shared__ unsigned pres[8];
    __shared__ float psum[4];
    int t = threadIdx.x;
    int b = t >> 5, j = t & 31;
    unsigned m = 0;
    const unsigned* p = bm + b * 128 + j * 4;
    #pragma unroll
    for (int k = 0; k < 4; ++k) m |= p[k];
    #pragma unroll
    for (int s = 16; s; s >>= 1) m |= __shfl_xor(m, s, 64);
    if (j == 0) pres[b] = m;
    __syncthreads();

    float v = 0.0f;
    if (t < 8 * NUM_CLASSES) {
        int bb = t / NUM_CLASSES, c = t % NUM_CLASSES;
        v = ((pres[bb] >> c) & 1u) ? lr[t] : LAMBDA * lr[168 + t];
    }
    #pragma unroll
    for (int s = 32; s; s >>= 1) v += __shfl_xor(v, s, 64);
    if ((t & 63) == 0) psum[t >> 6] = v;
    __syncthreads();
    if (t == 0) out[0] = (psum[0] + psum[1] + psum[2] + psum[3]) * 0.125f;
}

extern "C" void kernel_launch(void* const* d_in, const int* in_sizes, int n_in,
                              void* d_out, int out_size, void* d_ws, size_t ws_size,
                              hipStream_t stream) {
    const float* caps   = (const float*)d_in[0];  // [8,21,16] f32
    const int*   labels = (const int*)d_in[1];    // [8,512,512] i32
    float* out = (float*)d_out;
    unsigned* bm = (unsigned*)d_ws;                         // 1024 words
    float* lr = (float*)((char*)d_ws + 4096);               // 336 floats

    caps_fused1<<<257, 256, 0, stream>>>(labels, caps, bm, lr);
    caps_finalize<<<1, 256, 0, stream>>>(bm, lr, out);
}